// Round 2
// baseline (1584.658 us; speedup 1.0000x reference)
//
#include <hip/hip_runtime.h>
#include <stdint.h>

typedef unsigned short u16;
typedef __bf16 bf16x8 __attribute__((ext_vector_type(8)));
typedef float f32x4 __attribute__((ext_vector_type(4)));

#define AS1 __attribute__((address_space(1)))
#define AS3 __attribute__((address_space(3)))

enum {
  B_ = 2, S_ = 1024, U_ = 1024, H_ = 16, D_ = 64,
  NT_ = 32000, MEM_ = 576, FF_ = 4096, KL_ = 1600,
  BS_ = 2048, BKL_ = 3200
};

__device__ __forceinline__ u16 f2b(float f) {
  uint32_t u = __builtin_bit_cast(uint32_t, f);
  u = (u + 0x7fffu + ((u >> 16) & 1u)) >> 16;
  return (u16)u;
}
__device__ __forceinline__ float b2f(u16 h) {
  uint32_t u = ((uint32_t)h) << 16;
  return __builtin_bit_cast(float, u);
}

// ---------------- block reduction helpers (256 threads = 4 waves) -------------
__device__ __forceinline__ float block_sum(float v, volatile float* red) {
  int lane = threadIdx.x & 63, wv = threadIdx.x >> 6;
#pragma unroll
  for (int o = 32; o; o >>= 1) v += __shfl_xor(v, o, 64);
  if (lane == 0) red[wv] = v;
  __syncthreads();
  v = red[0] + red[1] + red[2] + red[3];
  __syncthreads();
  return v;
}
__device__ __forceinline__ float block_max(float v, volatile float* red) {
  int lane = threadIdx.x & 63, wv = threadIdx.x >> 6;
#pragma unroll
  for (int o = 32; o; o >>= 1) v = fmaxf(v, __shfl_xor(v, o, 64));
  if (lane == 0) red[wv] = v;
  __syncthreads();
  v = fmaxf(fmaxf(red[0], red[1]), fmaxf(red[2], red[3]));
  __syncthreads();
  return v;
}

// ---------------- generic bf16 MFMA GEMM: C = A(MxK) @ Bt(NxK)^T --------------
// A, Bt bf16, k contiguous. mode: 0 = plain (Cf and/or Cb, +bias), 1 = relu,
// 2 = rel-shift accumulate: Cb[gr][col-(S-1-gr)] += v (Transformer-XL shift).
// Batched over grid.z: z -> (bb = z/nh, hh = z%nh) with element-offsets.
// 2-phase double-buffered K-loop (T3-minimum): issue next K-tile's
// global_load_lds into buf^1 BEFORE computing buf, single barrier per K-step,
// so the barrier's vmcnt(0) drain lands after ~300cy of ds_read+MFMA work.
// kclamp_off>0: clamp K to m0+kclamp_off (causal zero-tail skip for att@v).
// flags&1: skip blocks fully above the causal mask (n0 > m0+127+MEM).
__global__ __launch_bounds__(256)
void k_gemm(const u16* __restrict__ A, const u16* __restrict__ Bt,
            float* __restrict__ Cf, u16* __restrict__ Cb,
            const float* __restrict__ bias,
            int M, int N, int K, int lda, int ldb, int ldc,
            long long sAb, long long sAh, long long sBb, long long sBh,
            long long sCb, long long sCh, int nh, int mode,
            int kclamp_off, int flags)
{
  __shared__ __align__(16) u16 As[2][128][64];  // 32 KB
  __shared__ __align__(16) u16 Bs[2][128][64];  // 32 KB

  int m0 = blockIdx.y * 128, n0 = blockIdx.x * 128;

  // causal tile skips (outputs in these tiles are never read downstream)
  if ((flags & 1) && n0 > m0 + 127 + MEM_) return;
  // rel-shift: all target cols tc = col-(S-1-gr) negative -> block writes nothing
  if (mode == 2 && n0 + m0 <= 768) return;   // max tc = n0+m0-769 < 0

  int z = blockIdx.z;
  int bb = z / nh, hh = z - bb * nh;
  A  += bb * sAb + hh * sAh;
  Bt += bb * sBb + hh * sBh;
  long long coff = bb * sCb + hh * sCh;

  int Keff = K;
  if (kclamp_off) { int kc = m0 + kclamp_off; if (kc < Keff) Keff = kc; }
  int nk = Keff >> 6;   // all K multiples of 64 here

  int t = threadIdx.x;
  int lane = t & 63, wave = t >> 6;
  int wm = (wave >> 1) * 64, wn = (wave & 1) * 64;
  int lrow = lane & 15, lq = lane >> 4;

  int srow = t >> 3;        // 0..31 staging row
  int scol = (t & 7) * 8;   // staging col (bf16 elems), 16B chunk

  auto STAGE = [&](int buf, int k0) {
#pragma unroll
    for (int it = 0; it < 4; ++it) {
      int r = srow + 32 * it;
      int gr = m0 + r;
      if (gr < M)
        __builtin_amdgcn_global_load_lds(
            (const AS1 void*)(A + (long long)gr * lda + k0 + scol),
            (AS3 void*)(&As[buf][r][scol]), 16, 0, 0);
      int gn = n0 + r;
      if (gn < N)
        __builtin_amdgcn_global_load_lds(
            (const AS1 void*)(Bt + (long long)gn * ldb + k0 + scol),
            (AS3 void*)(&Bs[buf][r][scol]), 16, 0, 0);
    }
  };

  f32x4 acc[4][4];
#pragma unroll
  for (int i = 0; i < 4; i++)
#pragma unroll
    for (int j = 0; j < 4; j++) acc[i][j] = (f32x4){0.f, 0.f, 0.f, 0.f};

  STAGE(0, 0);
  __syncthreads();          // drains vmcnt(0): buf0 ready

  int cur = 0;
  for (int kt = 0; kt < nk; ++kt) {
    if (kt + 1 < nk) STAGE(cur ^ 1, (kt + 1) << 6);   // prefetch next tile
#pragma unroll
    for (int ks = 0; ks < 2; ++ks) {
      int kk = ks * 32 + lq * 8;
      bf16x8 av[4], bv[4];
#pragma unroll
      for (int i = 0; i < 4; i++) av[i] = *(const bf16x8*)(&As[cur][wm + i * 16 + lrow][kk]);
#pragma unroll
      for (int j = 0; j < 4; j++) bv[j] = *(const bf16x8*)(&Bs[cur][wn + j * 16 + lrow][kk]);
#pragma unroll
      for (int i = 0; i < 4; i++)
#pragma unroll
        for (int j = 0; j < 4; j++)
          acc[i][j] = __builtin_amdgcn_mfma_f32_16x16x32_bf16(av[i], bv[j], acc[i][j], 0, 0, 0);
    }
    __syncthreads();        // drains vmcnt(0): next buf ready; this buf's reads done
    cur ^= 1;
  }

  // epilogue: D[row][col], col = lane&15, row = (lane>>4)*4 + r
#pragma unroll
  for (int j = 0; j < 4; j++) {
    int col = n0 + wn + j * 16 + lrow;
    if (col >= N) continue;
    float bvv = bias ? bias[col] : 0.f;
#pragma unroll
    for (int i = 0; i < 4; i++) {
      int row0 = m0 + wm + i * 16 + lq * 4;
#pragma unroll
      for (int r = 0; r < 4; r++) {
        int gr = row0 + r;
        if (gr >= M) continue;
        float v = acc[i][j][r] + bvv;
        if (mode == 2) {
          int tc = col - (S_ - 1 - gr);   // rel-shift target column
          if (tc >= 0) {
            long long idx = coff + (long long)gr * ldc + tc;
            Cb[idx] = f2b(b2f(Cb[idx]) + v);
          }
          continue;
        }
        if (mode == 1) v = fmaxf(v, 0.f);
        long long idx = coff + (long long)gr * ldc + col;
        if (Cf) Cf[idx] = v;
        if (Cb) Cb[idx] = f2b(v);
      }
    }
  }
}

// -------- embed gather*sqrt(U) + concat(memory, x) into bf16 (and x fp32) -----
__global__ void k_embed(const int* __restrict__ tokens, const float* __restrict__ memory,
                        const float* __restrict__ table, u16* __restrict__ fullbf,
                        u16* __restrict__ xbf, float* __restrict__ xf)
{
  int row = blockIdx.x;               // 0..B*KL-1
  int b = row / KL_, jk = row - b * KL_;
  int c = threadIdx.x * 4;
  u16* dst = fullbf + (size_t)row * U_ + c;
  if (jk < MEM_) {
    float4 v = *(const float4*)(memory + ((size_t)b * MEM_ + jk) * U_ + c);
    dst[0] = f2b(v.x); dst[1] = f2b(v.y); dst[2] = f2b(v.z); dst[3] = f2b(v.w);
  } else {
    int i = jk - MEM_;
    int tok = tokens[b * S_ + i];
    float4 v = *(const float4*)(table + (size_t)tok * U_ + c);
    v.x *= 32.f; v.y *= 32.f; v.z *= 32.f; v.w *= 32.f;
    dst[0] = f2b(v.x); dst[1] = f2b(v.y); dst[2] = f2b(v.z); dst[3] = f2b(v.w);
    size_t xi = ((size_t)b * S_ + i) * U_ + c;
    *(float4*)(xf + xi) = v;
    u16* xd = xbf + xi;
    xd[0] = f2b(v.x); xd[1] = f2b(v.y); xd[2] = f2b(v.z); xd[3] = f2b(v.w);
  }
}

// -------- sinusoidal relative positions (K,U), descending positions -----------
__global__ void k_relpos(u16* __restrict__ relbf)
{
  int m = blockIdx.x;
  float pos = (float)(KL_ - 1 - m);
  const float c0 = 9.210340371976184f / 512.0f;  // ln(10000)/512
  for (int c = threadIdx.x; c < U_; c += 256) {
    int i = (c < 512) ? c : (c - 512);
    float inv = expf(-(float)i * c0);
    float arg = pos * inv;
    float v = (c < 512) ? sinf(arg) : cosf(arg);
    relbf[(size_t)m * U_ + c] = f2b(v);
  }
}

// -------- q (fp32, bq already added) + bias_context / bias_relative -> bf16 ---
__global__ void k_qbias(const float* __restrict__ qf, const float* __restrict__ bc,
                        const float* __restrict__ br, u16* __restrict__ qc,
                        u16* __restrict__ qr)
{
  int c = threadIdx.x * 4;
  size_t idx = (size_t)blockIdx.x * U_ + c;
  float4 q = *(const float4*)(qf + idx);
  float4 vc = *(const float4*)(bc + c);
  float4 vr = *(const float4*)(br + c);
  qc[idx + 0] = f2b(q.x + vc.x); qc[idx + 1] = f2b(q.y + vc.y);
  qc[idx + 2] = f2b(q.z + vc.z); qc[idx + 3] = f2b(q.w + vc.w);
  qr[idx + 0] = f2b(q.x + vr.x); qr[idx + 1] = f2b(q.y + vr.y);
  qr[idx + 2] = f2b(q.z + vr.z); qr[idx + 3] = f2b(q.w + vr.w);
}

// -------- fp32 (R,C) -> bf16 (C,R) transpose ---------------------------------
__global__ void k_transpose(const float* __restrict__ in, u16* __restrict__ out,
                            int R, int C)
{
  __shared__ float tile[32][33];
  int tx = threadIdx.x & 31, ty = threadIdx.x >> 5;   // 32x8
  int c0 = blockIdx.x * 32, r0 = blockIdx.y * 32;
#pragma unroll
  for (int i = 0; i < 4; i++) {
    int r = r0 + ty + i * 8;
    tile[ty + i * 8][tx] = in[(size_t)r * C + c0 + tx];
  }
  __syncthreads();
#pragma unroll
  for (int i = 0; i < 4; i++) {
    int c = c0 + ty + i * 8;
    out[(size_t)c * R + r0 + tx] = f2b(tile[tx][ty + i * 8]);
  }
}

// -------- v slice of kv (B,K,2U) -> vT (B,H,D,K) bf16 transpose ---------------
__global__ void k_vt(const u16* __restrict__ kvbf, u16* __restrict__ vT)
{
  __shared__ u16 tile[32][33];
  int z = blockIdx.z;                 // b*H + h
  int b = z >> 4, h = z & 15;
  int tx = threadIdx.x & 31, ty = threadIdx.x >> 5;
  int j0 = blockIdx.x * 32, d0 = blockIdx.y * 32;
#pragma unroll
  for (int i = 0; i < 4; i++) {
    int j = j0 + ty + i * 8;
    tile[ty + i * 8][tx] = kvbf[((size_t)(b * KL_ + j)) * (2 * U_) + U_ + h * 64 + d0 + tx];
  }
  __syncthreads();
#pragma unroll
  for (int i = 0; i < 4; i++) {
    int d = d0 + ty + i * 8;
    vT[((size_t)(z * 64 + d)) * KL_ + j0 + tx] = tile[tx][ty + i * 8];
  }
}

// -------- attention softmax (scores already contain a_c + shifted a_r) --------
// att[i,j] = softmax_j( C1[i,j] / 8 ), masked to j <= i + MEM.
// Only j < jhi = tile_m0 + MEM + 128 is ever read downstream (att@v K-clamp),
// so we neither read nor write beyond it.
__global__ void k_attnsm(u16* __restrict__ C1)
{
  __shared__ float red[4];
  int i = blockIdx.x, z = blockIdx.y;
  size_t base = ((size_t)z * S_ + i) * KL_;
  int jmax = i + MEM_;
  int jhi = ((i >> 7) << 7) + MEM_ + 128;
  if (jhi > KL_) jhi = KL_;
  int t = threadIdx.x;
  float vloc[7];
  float lmax = -1e30f;
  int cnt = 0;
  for (int j = t; j < jhi; j += 256, ++cnt) {
    float v = -1e30f;
    if (j <= jmax) v = b2f(C1[base + j]) * 0.125f;
    vloc[cnt] = v;
    lmax = fmaxf(lmax, v);
  }
  float M = block_max(lmax, red);
  float lsum = 0.f;
  for (int c = 0; c < cnt; ++c) lsum += expf(vloc[c] - M);
  float L = block_sum(lsum, red);
  float inv = 1.f / L;
  cnt = 0;
  for (int j = t; j < jhi; j += 256, ++cnt)
    C1[base + j] = f2b(expf(vloc[cnt] - M) * inv);
}

// -------- residual add + LayerNorm -------------------------------------------
__global__ void k_ln(const float* __restrict__ a, const float* __restrict__ b,
                     const float* __restrict__ g, const float* __restrict__ be,
                     float* __restrict__ yf, u16* __restrict__ yb)
{
  __shared__ float red[4];
  int c = threadIdx.x * 4;
  size_t idx = (size_t)blockIdx.x * U_ + c;
  float4 va = *(const float4*)(a + idx);
  float4 vb = *(const float4*)(b + idx);
  float s0 = va.x + vb.x, s1 = va.y + vb.y, s2 = va.z + vb.z, s3 = va.w + vb.w;
  float sum = block_sum(s0 + s1 + s2 + s3, red);
  float sq  = block_sum(s0 * s0 + s1 * s1 + s2 * s2 + s3 * s3, red);
  float mean = sum * (1.0f / U_);
  float var = sq * (1.0f / U_) - mean * mean;
  float rs = rsqrtf(var + 1e-5f);
  float4 vg = *(const float4*)(g + c);
  float4 vbe = *(const float4*)(be + c);
  float y0 = (s0 - mean) * rs * vg.x + vbe.x;
  float y1 = (s1 - mean) * rs * vg.y + vbe.y;
  float y2 = (s2 - mean) * rs * vg.z + vbe.z;
  float y3 = (s3 - mean) * rs * vg.w + vbe.w;
  if (yf) { float4 o = make_float4(y0, y1, y2, y3); *(float4*)(yf + idx) = o; }
  yb[idx + 0] = f2b(y0); yb[idx + 1] = f2b(y1);
  yb[idx + 2] = f2b(y2); yb[idx + 3] = f2b(y3);
}

// -------- final softmax over NT=32000, in-place on fp32 logits ----------------
__global__ void k_outsm(float* __restrict__ logits)
{
  __shared__ float redm[4], redl[4];
  int row = blockIdx.x, t = threadIdx.x;
  float* lp = logits + (size_t)row * NT_;
  float m = -1e30f, l = 0.f;
  for (int j = t; j < NT_; j += 256) {
    float x = lp[j];
    if (x > m) { l = l * expf(m - x) + 1.f; m = x; }
    else       { l += expf(x - m); }
  }
  int lane = t & 63, wv = t >> 6;
#pragma unroll
  for (int o = 32; o; o >>= 1) {
    float mo = __shfl_xor(m, o, 64), lo = __shfl_xor(l, o, 64);
    float mn = fmaxf(m, mo);
    l = l * expf(m - mn) + lo * expf(mo - mn);
    m = mn;
  }
  if (lane == 0) { redm[wv] = m; redl[wv] = l; }
  __syncthreads();
  float M = fmaxf(fmaxf(redm[0], redm[1]), fmaxf(redm[2], redm[3]));
  float L = redl[0] * expf(redm[0] - M) + redl[1] * expf(redm[1] - M) +
            redl[2] * expf(redm[2] - M) + redl[3] * expf(redm[3] - M);
  float inv = 1.f / L;
  for (int j = t; j < NT_; j += 256)
    lp[j] = expf(lp[j] - M) * inv;
}

// ------------------------------ host driver ----------------------------------
static void gemm(hipStream_t st, const u16* A, const u16* Bt, float* Cf, u16* Cb,
                 const float* bias, int M, int N, int K, int lda, int ldb, int ldc,
                 long long sAb, long long sAh, long long sBb, long long sBh,
                 long long sCb, long long sCh, int nb, int nh, int mode,
                 int kclamp_off = 0, int flags = 0)
{
  dim3 g((N + 127) / 128, (M + 127) / 128, nb * nh);
  k_gemm<<<g, 256, 0, st>>>(A, Bt, Cf, Cb, bias, M, N, K, lda, ldb, ldc,
                            sAb, sAh, sBb, sBh, sCb, sCh, nh, mode,
                            kclamp_off, flags);
}

extern "C" void kernel_launch(void* const* d_in, const int* in_sizes, int n_in,
                              void* d_out, int out_size, void* d_ws, size_t ws_size,
                              hipStream_t stream)
{
  const int*   tokens = (const int*)d_in[0];
  const float* memory = (const float*)d_in[1];
  const float* table  = (const float*)d_in[2];
  const float* Wq   = (const float*)d_in[3];
  const float* Wkv  = (const float*)d_in[4];
  const float* Wr   = (const float*)d_in[5];
  const float* Wo   = (const float*)d_in[6];
  const float* bq   = (const float*)d_in[7];
  const float* bkv  = (const float*)d_in[8];
  const float* br   = (const float*)d_in[9];
  const float* bo   = (const float*)d_in[10];
  const float* bctx = (const float*)d_in[11];
  const float* brel = (const float*)d_in[12];
  const float* ln1g = (const float*)d_in[13];
  const float* ln1b = (const float*)d_in[14];
  const float* W1   = (const float*)d_in[15];
  const float* b1   = (const float*)d_in[16];
  const float* W2   = (const float*)d_in[17];
  const float* b2   = (const float*)d_in[18];
  const float* ln2g = (const float*)d_in[19];
  const float* ln2b = (const float*)d_in[20];
  const float* Wout = (const float*)d_in[21];
  const float* bout = (const float*)d_in[22];
  float* out = (float*)d_out;

  char* w = (char*)d_ws;
  size_t off = 0;
  auto carve = [&](size_t bytes) -> char* {
    char* p = w + off;
    off = (off + bytes + 255) & ~(size_t)255;
    return p;
  };

  u16*  WqT    = (u16*)carve((size_t)U_ * U_ * 2);
  u16*  WkvT   = (u16*)carve((size_t)2 * U_ * U_ * 2);
  u16*  WrT    = (u16*)carve((size_t)U_ * U_ * 2);
  u16*  WoT    = (u16*)carve((size_t)U_ * U_ * 2);
  u16*  W1T    = (u16*)carve((size_t)FF_ * U_ * 2);
  u16*  W2T    = (u16*)carve((size_t)U_ * FF_ * 2);
  float* xf    = (float*)carve((size_t)BS_ * U_ * 4);
  u16*  xbf    = (u16*)carve((size_t)BS_ * U_ * 2);
  u16*  fullbf = (u16*)carve((size_t)BKL_ * U_ * 2);
  u16*  relbf  = (u16*)carve((size_t)KL_ * U_ * 2);
  float* qf    = (float*)carve((size_t)BS_ * U_ * 4);
  u16*  qcbf   = (u16*)carve((size_t)BS_ * U_ * 2);
  u16*  qrbf   = (u16*)carve((size_t)BS_ * U_ * 2);
  u16*  kvbf   = (u16*)carve((size_t)BKL_ * 2 * U_ * 2);
  u16*  vT     = (u16*)carve((size_t)B_ * H_ * D_ * KL_ * 2);
  u16*  rW     = (u16*)carve((size_t)KL_ * U_ * 2);
  u16*  attout = (u16*)carve((size_t)BS_ * U_ * 2);
  float* of    = (float*)carve((size_t)BS_ * U_ * 4);
  float* h1f   = (float*)carve((size_t)BS_ * U_ * 4);
  u16*  h1bf   = (u16*)carve((size_t)BS_ * U_ * 2);
  u16*  ff1bf  = (u16*)carve((size_t)BS_ * FF_ * 2);
  float* ff2f  = (float*)carve((size_t)BS_ * U_ * 4);
  u16*  h2bf   = (u16*)carve((size_t)BS_ * U_ * 2);

  // big region: C1 scores during attention; WoutT (64 MB) overlays it after
  size_t scoreBytes = (size_t)B_ * H_ * S_ * KL_ * 2;   // 104,857,600
  char* big = carve(scoreBytes);
  u16* C1    = (u16*)big;
  u16* WoutT = (u16*)big;

  if (off > ws_size) return;  // workspace too small: fail cleanly, don't fault

  // ---- weight transposes (fp32 -> bf16, (R,C) -> (C,R)) ----
  k_transpose<<<dim3(U_ / 32, U_ / 32), 256, 0, stream>>>(Wq, WqT, U_, U_);
  k_transpose<<<dim3(2 * U_ / 32, U_ / 32), 256, 0, stream>>>(Wkv, WkvT, U_, 2 * U_);
  k_transpose<<<dim3(U_ / 32, U_ / 32), 256, 0, stream>>>(Wr, WrT, U_, U_);
  k_transpose<<<dim3(U_ / 32, U_ / 32), 256, 0, stream>>>(Wo, WoT, U_, U_);
  k_transpose<<<dim3(FF_ / 32, U_ / 32), 256, 0, stream>>>(W1, W1T, U_, FF_);
  k_transpose<<<dim3(U_ / 32, FF_ / 32), 256, 0, stream>>>(W2, W2T, FF_, U_);

  k_embed<<<dim3(BKL_), 256, 0, stream>>>(tokens, memory, table, fullbf, xbf, xf);
  k_relpos<<<dim3(KL_), 256, 0, stream>>>(relbf);

  // q = x@Wq + bq (fp32)
  gemm(stream, xbf, WqT, qf, nullptr, bq, BS_, U_, U_, U_, U_, U_,
       0, 0, 0, 0, 0, 0, 1, 1, 0);
  k_qbias<<<dim3(BS_), 256, 0, stream>>>(qf, bctx, brel, qcbf, qrbf);

  // kv = full@Wkv + bkv (bf16)
  gemm(stream, fullbf, WkvT, nullptr, kvbf, bkv, BKL_, 2 * U_, U_, U_, U_, 2 * U_,
       0, 0, 0, 0, 0, 0, 1, 1, 0);
  k_vt<<<dim3(KL_ / 32, 2, B_ * H_), 256, 0, stream>>>(kvbf, vT);

  // rW = rel@Wr + br (bf16)
  gemm(stream, relbf, WrT, nullptr, rW, br, KL_, U_, U_, U_, U_, U_,
       0, 0, 0, 0, 0, 0, 1, 1, 0);

  // C1 = q_c @ k^T  (batched over b,h; fully-masked tiles skipped)
  gemm(stream, qcbf, kvbf, nullptr, C1, nullptr,
       S_, KL_, D_, U_, 2 * U_, KL_,
       (long long)S_ * U_, 64, (long long)KL_ * 2 * U_, 64,
       (long long)H_ * S_ * KL_, (long long)S_ * KL_, B_, H_, 0, 0, 1);
  // C1 += rel-shift(q_r @ r^T)  (mode 2 epilogue; all-tc<0 tiles skipped)
  gemm(stream, qrbf, rW, nullptr, C1, nullptr,
       S_, KL_, D_, U_, U_, KL_,
       (long long)S_ * U_, 64, 0, 64,
       (long long)H_ * S_ * KL_, (long long)S_ * KL_, B_, H_, 2);

  k_attnsm<<<dim3(S_, B_ * H_), 256, 0, stream>>>(C1);

  // attout = att @ v (bf16, written as (B,S,H,D) == (B,S,U)); K clamped to
  // m0+MEM+128 (everything beyond is exactly zero after softmax)
  gemm(stream, C1, vT, nullptr, attout, nullptr,
       S_, D_, KL_, KL_, KL_, U_,
       (long long)H_ * S_ * KL_, (long long)S_ * KL_,
       (long long)H_ * D_ * KL_, (long long)D_ * KL_,
       (long long)S_ * U_, 64, B_, H_, 0, MEM_ + 128, 0);

  // of = attout@Wo + bo (fp32)
  gemm(stream, attout, WoT, of, nullptr, bo, BS_, U_, U_, U_, U_, U_,
       0, 0, 0, 0, 0, 0, 1, 1, 0);
  k_ln<<<dim3(BS_), 256, 0, stream>>>(xf, of, ln1g, ln1b, h1f, h1bf);

  // ff1 = relu(h1@W1 + b1) (bf16)
  gemm(stream, h1bf, W1T, nullptr, ff1bf, b1, BS_, FF_, U_, U_, U_, FF_,
       0, 0, 0, 0, 0, 0, 1, 1, 1);
  // ff2 = ff1@W2 + b2 (fp32)
  gemm(stream, ff1bf, W2T, ff2f, nullptr, b2, BS_, U_, FF_, FF_, FF_, U_,
       0, 0, 0, 0, 0, 0, 1, 1, 0);
  k_ln<<<dim3(BS_), 256, 0, stream>>>(h1f, ff2f, ln2g, ln2b, nullptr, h2bf);

  // scores region free now (att consumed) -> WoutT overlays it
  k_transpose<<<dim3(NT_ / 32, U_ / 32), 256, 0, stream>>>(Wout, WoutT, U_, NT_);

  // logits = h2@Wout + bout, fp32 straight into d_out; softmax in place
  gemm(stream, h2bf, WoutT, out, nullptr, bout, BS_, NT_, U_, U_, U_, NT_,
       0, 0, 0, 0, 0, 0, 1, 1, 0);
  k_outsm<<<dim3(BS_), 256, 0, stream>>>(out);
}

// Round 3
// 1379.615 us; speedup vs baseline: 1.1486x; 1.1486x over previous
//
#include <hip/hip_runtime.h>
#include <stdint.h>

typedef unsigned short u16;
typedef __bf16 bf16x8 __attribute__((ext_vector_type(8)));
typedef float f32x4 __attribute__((ext_vector_type(4)));

#define AS1 __attribute__((address_space(1)))
#define AS3 __attribute__((address_space(3)))

enum {
  B_ = 2, S_ = 1024, U_ = 1024, H_ = 16, D_ = 64,
  NT_ = 32000, MEM_ = 576, FF_ = 4096, KL_ = 1600,
  BS_ = 2048, BKL_ = 3200
};

__device__ __forceinline__ u16 f2b(float f) {
  uint32_t u = __builtin_bit_cast(uint32_t, f);
  u = (u + 0x7fffu + ((u >> 16) & 1u)) >> 16;
  return (u16)u;
}
__device__ __forceinline__ float b2f(u16 h) {
  uint32_t u = ((uint32_t)h) << 16;
  return __builtin_bit_cast(float, u);
}

// ---------------- block reduction helpers (256 threads = 4 waves) -------------
__device__ __forceinline__ float block_sum(float v, volatile float* red) {
  int lane = threadIdx.x & 63, wv = threadIdx.x >> 6;
#pragma unroll
  for (int o = 32; o; o >>= 1) v += __shfl_xor(v, o, 64);
  if (lane == 0) red[wv] = v;
  __syncthreads();
  v = red[0] + red[1] + red[2] + red[3];
  __syncthreads();
  return v;
}
__device__ __forceinline__ float block_max(float v, volatile float* red) {
  int lane = threadIdx.x & 63, wv = threadIdx.x >> 6;
#pragma unroll
  for (int o = 32; o; o >>= 1) v = fmaxf(v, __shfl_xor(v, o, 64));
  if (lane == 0) red[wv] = v;
  __syncthreads();
  v = fmaxf(fmaxf(red[0], red[1]), fmaxf(red[2], red[3]));
  __syncthreads();
  return v;
}

// ---------------- generic bf16 MFMA GEMM: C = A(MxK) @ Bt(NxK)^T --------------
// A, Bt bf16, k contiguous. mode: 0 = plain (Cf and/or Cb, +bias), 1 = relu,
// 2 = rel-shift accumulate: Cb[gr][col-(S-1-gr)] += v (Transformer-XL shift).
// Batched over grid.z: z -> (bb = z/nh, hh = z%nh) with element-offsets.
// Single-buffered K-loop (R0 structure: proven fastest here; both the XCD
// swizzle (R1) and LDS double-buffer (R2) measured slower — not BW-bound,
// and 64KB LDS halves occupancy).
// kclamp_off>0: clamp K to m0+kclamp_off (causal zero-tail skip for att@v).
// flags&1: skip blocks fully above the causal mask (n0 > m0+127+MEM).
// PART=1: additionally emit per-block softmax partials (row max & sum of exp)
// into Pm/Pl[M][gridDim.x] — fuses pass 1 of the final softmax into the
// Wout GEMM epilogue. Separate instantiation so PART=0 codegen is untouched.
template <int PART>
__global__ __launch_bounds__(256)
void k_gemm(const u16* __restrict__ A, const u16* __restrict__ Bt,
            float* __restrict__ Cf, u16* __restrict__ Cb,
            const float* __restrict__ bias,
            int M, int N, int K, int lda, int ldb, int ldc,
            long long sAb, long long sAh, long long sBb, long long sBh,
            long long sCb, long long sCh, int nh, int mode,
            int kclamp_off, int flags,
            float* __restrict__ Pm, float* __restrict__ Pl)
{
  __shared__ __align__(16) u16 As[128][64];  // 16 KB
  __shared__ __align__(16) u16 Bs[128][64];  // 16 KB

  int m0 = blockIdx.y * 128, n0 = blockIdx.x * 128;

  // causal tile skips (outputs in these tiles are never read downstream)
  if ((flags & 1) && n0 > m0 + 127 + MEM_) return;
  // rel-shift: all target cols tc = col-(S-1-gr) negative -> block writes nothing
  if (mode == 2 && n0 + m0 <= 768) return;   // max tc = n0+m0-769 < 0

  int z = blockIdx.z;
  int bb = z / nh, hh = z - bb * nh;
  A  += bb * sAb + hh * sAh;
  Bt += bb * sBb + hh * sBh;
  long long coff = bb * sCb + hh * sCh;

  int Keff = K;
  if (kclamp_off) { int kc = m0 + kclamp_off; if (kc < Keff) Keff = kc; }

  int t = threadIdx.x;
  int lane = t & 63, wave = t >> 6;
  int wm = (wave >> 1) * 64, wn = (wave & 1) * 64;
  int lrow = lane & 15, lq = lane >> 4;

  int srow = t >> 3;        // 0..31 staging row
  int scol = (t & 7) * 8;   // staging col (bf16 elems), 16B chunk

  f32x4 acc[4][4];
#pragma unroll
  for (int i = 0; i < 4; i++)
#pragma unroll
    for (int j = 0; j < 4; j++) acc[i][j] = (f32x4){0.f, 0.f, 0.f, 0.f};

  for (int k0 = 0; k0 < Keff; k0 += 64) {
#pragma unroll
    for (int it = 0; it < 4; ++it) {
      int r = srow + 32 * it;
      int gr = m0 + r;
      if (gr < M)
        __builtin_amdgcn_global_load_lds(
            (const AS1 void*)(A + (long long)gr * lda + k0 + scol),
            (AS3 void*)(&As[r][scol]), 16, 0, 0);
      int gn = n0 + r;
      if (gn < N)
        __builtin_amdgcn_global_load_lds(
            (const AS1 void*)(Bt + (long long)gn * ldb + k0 + scol),
            (AS3 void*)(&Bs[r][scol]), 16, 0, 0);
    }
    __syncthreads();
#pragma unroll
    for (int ks = 0; ks < 2; ++ks) {
      int kk = ks * 32 + lq * 8;
      bf16x8 av[4], bv[4];
#pragma unroll
      for (int i = 0; i < 4; i++) av[i] = *(const bf16x8*)(&As[wm + i * 16 + lrow][kk]);
#pragma unroll
      for (int j = 0; j < 4; j++) bv[j] = *(const bf16x8*)(&Bs[wn + j * 16 + lrow][kk]);
#pragma unroll
      for (int i = 0; i < 4; i++)
#pragma unroll
        for (int j = 0; j < 4; j++)
          acc[i][j] = __builtin_amdgcn_mfma_f32_16x16x32_bf16(av[i], bv[j], acc[i][j], 0, 0, 0);
    }
    __syncthreads();
  }

  if (PART) {
    // Wout path: exact shape (no bounds checks), fp32 out + bias, and
    // per-block softmax partials. LDS of As (dead now) reused for the
    // cross-wave row merge.
    float* pmf = (float*)(&As[0][0]);          // 128 rows x 2 col-halves
    float* plf = pmf + 256;
    int wh = wave & 1;
#pragma unroll
    for (int i = 0; i < 4; i++) {
#pragma unroll
      for (int r = 0; r < 4; r++) {
        int row = wm + i * 16 + lq * 4 + r;    // 0..127 within block
        int gr = m0 + row;
        float v[4];
        float vmax = -1e30f;
#pragma unroll
        for (int j = 0; j < 4; j++) {
          int col = n0 + wn + j * 16 + lrow;
          v[j] = acc[i][j][r] + bias[col];
          Cf[coff + (long long)gr * ldc + col] = v[j];
          vmax = fmaxf(vmax, v[j]);
        }
#pragma unroll
        for (int o = 1; o < 16; o <<= 1) vmax = fmaxf(vmax, __shfl_xor(vmax, o, 64));
        float s = 0.f;
#pragma unroll
        for (int j = 0; j < 4; j++) s += expf(v[j] - vmax);
#pragma unroll
        for (int o = 1; o < 16; o <<= 1) s += __shfl_xor(s, o, 64);
        if (lrow == 0) { pmf[row * 2 + wh] = vmax; plf[row * 2 + wh] = s; }
      }
    }
    __syncthreads();
    int nxt = gridDim.x;
    for (int tt = t; tt < 128; tt += 256) {
      float ma = pmf[tt * 2], mb = pmf[tt * 2 + 1];
      float Mx = fmaxf(ma, mb);
      float L = plf[tt * 2] * expf(ma - Mx) + plf[tt * 2 + 1] * expf(mb - Mx);
      Pm[(size_t)(m0 + tt) * nxt + blockIdx.x] = Mx;
      Pl[(size_t)(m0 + tt) * nxt + blockIdx.x] = L;
    }
    return;
  }

  // epilogue: D[row][col], col = lane&15, row = (lane>>4)*4 + r
#pragma unroll
  for (int j = 0; j < 4; j++) {
    int col = n0 + wn + j * 16 + lrow;
    if (col >= N) continue;
    float bvv = bias ? bias[col] : 0.f;
#pragma unroll
    for (int i = 0; i < 4; i++) {
      int row0 = m0 + wm + i * 16 + lq * 4;
#pragma unroll
      for (int r = 0; r < 4; r++) {
        int gr = row0 + r;
        if (gr >= M) continue;
        float v = acc[i][j][r] + bvv;
        if (mode == 2) {
          int tc = col - (S_ - 1 - gr);   // rel-shift target column
          if (tc >= 0) {
            long long idx = coff + (long long)gr * ldc + tc;
            Cb[idx] = f2b(b2f(Cb[idx]) + v);
          }
          continue;
        }
        if (mode == 1) v = fmaxf(v, 0.f);
        long long idx = coff + (long long)gr * ldc + col;
        if (Cf) Cf[idx] = v;
        if (Cb) Cb[idx] = f2b(v);
      }
    }
  }
}

// -------- embed gather*sqrt(U) + concat(memory, x) into bf16 (and x fp32) -----
__global__ void k_embed(const int* __restrict__ tokens, const float* __restrict__ memory,
                        const float* __restrict__ table, u16* __restrict__ fullbf,
                        u16* __restrict__ xbf, float* __restrict__ xf)
{
  int row = blockIdx.x;               // 0..B*KL-1
  int b = row / KL_, jk = row - b * KL_;
  int c = threadIdx.x * 4;
  u16* dst = fullbf + (size_t)row * U_ + c;
  if (jk < MEM_) {
    float4 v = *(const float4*)(memory + ((size_t)b * MEM_ + jk) * U_ + c);
    dst[0] = f2b(v.x); dst[1] = f2b(v.y); dst[2] = f2b(v.z); dst[3] = f2b(v.w);
  } else {
    int i = jk - MEM_;
    int tok = tokens[b * S_ + i];
    float4 v = *(const float4*)(table + (size_t)tok * U_ + c);
    v.x *= 32.f; v.y *= 32.f; v.z *= 32.f; v.w *= 32.f;
    dst[0] = f2b(v.x); dst[1] = f2b(v.y); dst[2] = f2b(v.z); dst[3] = f2b(v.w);
    size_t xi = ((size_t)b * S_ + i) * U_ + c;
    *(float4*)(xf + xi) = v;
    u16* xd = xbf + xi;
    xd[0] = f2b(v.x); xd[1] = f2b(v.y); xd[2] = f2b(v.z); xd[3] = f2b(v.w);
  }
}

// -------- sinusoidal relative positions (K,U), descending positions -----------
__global__ void k_relpos(u16* __restrict__ relbf)
{
  int m = blockIdx.x;
  float pos = (float)(KL_ - 1 - m);
  const float c0 = 9.210340371976184f / 512.0f;  // ln(10000)/512
  for (int c = threadIdx.x; c < U_; c += 256) {
    int i = (c < 512) ? c : (c - 512);
    float inv = expf(-(float)i * c0);
    float arg = pos * inv;
    float v = (c < 512) ? sinf(arg) : cosf(arg);
    relbf[(size_t)m * U_ + c] = f2b(v);
  }
}

// -------- q (fp32, bq already added) + bias_context / bias_relative -> bf16 ---
__global__ void k_qbias(const float* __restrict__ qf, const float* __restrict__ bc,
                        const float* __restrict__ br, u16* __restrict__ qc,
                        u16* __restrict__ qr)
{
  int c = threadIdx.x * 4;
  size_t idx = (size_t)blockIdx.x * U_ + c;
  float4 q = *(const float4*)(qf + idx);
  float4 vc = *(const float4*)(bc + c);
  float4 vr = *(const float4*)(br + c);
  qc[idx + 0] = f2b(q.x + vc.x); qc[idx + 1] = f2b(q.y + vc.y);
  qc[idx + 2] = f2b(q.z + vc.z); qc[idx + 3] = f2b(q.w + vc.w);
  qr[idx + 0] = f2b(q.x + vr.x); qr[idx + 1] = f2b(q.y + vr.y);
  qr[idx + 2] = f2b(q.z + vr.z); qr[idx + 3] = f2b(q.w + vr.w);
}

// -------- fp32 (R,C) -> bf16 (C,R) transpose ---------------------------------
__global__ void k_transpose(const float* __restrict__ in, u16* __restrict__ out,
                            int R, int C)
{
  __shared__ float tile[32][33];
  int tx = threadIdx.x & 31, ty = threadIdx.x >> 5;   // 32x8
  int c0 = blockIdx.x * 32, r0 = blockIdx.y * 32;
#pragma unroll
  for (int i = 0; i < 4; i++) {
    int r = r0 + ty + i * 8;
    tile[ty + i * 8][tx] = in[(size_t)r * C + c0 + tx];
  }
  __syncthreads();
#pragma unroll
  for (int i = 0; i < 4; i++) {
    int c = c0 + ty + i * 8;
    out[(size_t)c * R + r0 + tx] = f2b(tile[tx][ty + i * 8]);
  }
}

// -------- v slice of kv (B,K,2U) -> vT (B,H,D,K) bf16 transpose ---------------
__global__ void k_vt(const u16* __restrict__ kvbf, u16* __restrict__ vT)
{
  __shared__ u16 tile[32][33];
  int z = blockIdx.z;                 // b*H + h
  int b = z >> 4, h = z & 15;
  int tx = threadIdx.x & 31, ty = threadIdx.x >> 5;
  int j0 = blockIdx.x * 32, d0 = blockIdx.y * 32;
#pragma unroll
  for (int i = 0; i < 4; i++) {
    int j = j0 + ty + i * 8;
    tile[ty + i * 8][tx] = kvbf[((size_t)(b * KL_ + j)) * (2 * U_) + U_ + h * 64 + d0 + tx];
  }
  __syncthreads();
#pragma unroll
  for (int i = 0; i < 4; i++) {
    int d = d0 + ty + i * 8;
    vT[((size_t)(z * 64 + d)) * KL_ + j0 + tx] = tile[tx][ty + i * 8];
  }
}

// -------- attention softmax (scores already contain a_c + shifted a_r) --------
// att[i,j] = softmax_j( C1[i,j] / 8 ), masked to j <= i + MEM.
// Only j < jhi = tile_m0 + MEM + 128 is ever read downstream (att@v K-clamp),
// so we neither read nor write beyond it.
__global__ void k_attnsm(u16* __restrict__ C1)
{
  __shared__ float red[4];
  int i = blockIdx.x, z = blockIdx.y;
  size_t base = ((size_t)z * S_ + i) * KL_;
  int jmax = i + MEM_;
  int jhi = ((i >> 7) << 7) + MEM_ + 128;
  if (jhi > KL_) jhi = KL_;
  int t = threadIdx.x;
  float vloc[7];
  float lmax = -1e30f;
  int cnt = 0;
  for (int j = t; j < jhi; j += 256, ++cnt) {
    float v = -1e30f;
    if (j <= jmax) v = b2f(C1[base + j]) * 0.125f;
    vloc[cnt] = v;
    lmax = fmaxf(lmax, v);
  }
  float M = block_max(lmax, red);
  float lsum = 0.f;
  for (int c = 0; c < cnt; ++c) lsum += expf(vloc[c] - M);
  float L = block_sum(lsum, red);
  float inv = 1.f / L;
  cnt = 0;
  for (int j = t; j < jhi; j += 256, ++cnt)
    C1[base + j] = f2b(expf(vloc[cnt] - M) * inv);
}

// -------- residual add + LayerNorm -------------------------------------------
__global__ void k_ln(const float* __restrict__ a, const float* __restrict__ b,
                     const float* __restrict__ g, const float* __restrict__ be,
                     float* __restrict__ yf, u16* __restrict__ yb)
{
  __shared__ float red[4];
  int c = threadIdx.x * 4;
  size_t idx = (size_t)blockIdx.x * U_ + c;
  float4 va = *(const float4*)(a + idx);
  float4 vb = *(const float4*)(b + idx);
  float s0 = va.x + vb.x, s1 = va.y + vb.y, s2 = va.z + vb.z, s3 = va.w + vb.w;
  float sum = block_sum(s0 + s1 + s2 + s3, red);
  float sq  = block_sum(s0 * s0 + s1 * s1 + s2 * s2 + s3 * s3, red);
  float mean = sum * (1.0f / U_);
  float var = sq * (1.0f / U_) - mean * mean;
  float rs = rsqrtf(var + 1e-5f);
  float4 vg = *(const float4*)(g + c);
  float4 vbe = *(const float4*)(be + c);
  float y0 = (s0 - mean) * rs * vg.x + vbe.x;
  float y1 = (s1 - mean) * rs * vg.y + vbe.y;
  float y2 = (s2 - mean) * rs * vg.z + vbe.z;
  float y3 = (s3 - mean) * rs * vg.w + vbe.w;
  if (yf) { float4 o = make_float4(y0, y1, y2, y3); *(float4*)(yf + idx) = o; }
  yb[idx + 0] = f2b(y0); yb[idx + 1] = f2b(y1);
  yb[idx + 2] = f2b(y2); yb[idx + 3] = f2b(y3);
}

// -------- final softmax over NT=32000, one pass using GEMM-emitted partials ---
__global__ void k_outsm2(float* __restrict__ logits,
                         const float* __restrict__ Pm,
                         const float* __restrict__ Pl, int nt)
{
  __shared__ float redm[4], redl[4];
  int row = blockIdx.x, t = threadIdx.x;
  // merge per-tile partials (nt = 250)
  float m = -1e30f, l = 0.f;
  for (int j = t; j < nt; j += 256) {
    float mj = Pm[(size_t)row * nt + j], lj = Pl[(size_t)row * nt + j];
    float mn = fmaxf(m, mj);
    l = l * expf(m - mn) + lj * expf(mj - mn);
    m = mn;
  }
  int lane = t & 63, wv = t >> 6;
#pragma unroll
  for (int o = 32; o; o >>= 1) {
    float mo = __shfl_xor(m, o, 64), lo = __shfl_xor(l, o, 64);
    float mn = fmaxf(m, mo);
    l = l * expf(m - mn) + lo * expf(mo - mn);
    m = mn;
  }
  if (lane == 0) { redm[wv] = m; redl[wv] = l; }
  __syncthreads();
  float M = fmaxf(fmaxf(redm[0], redm[1]), fmaxf(redm[2], redm[3]));
  float L = redl[0] * expf(redm[0] - M) + redl[1] * expf(redm[1] - M) +
            redl[2] * expf(redm[2] - M) + redl[3] * expf(redm[3] - M);
  float inv = 1.f / L;
  float* lp = logits + (size_t)row * NT_;
  for (int j = t; j < NT_; j += 256)
    lp[j] = expf(lp[j] - M) * inv;
}

// ------------------------------ host driver ----------------------------------
static void gemm(hipStream_t st, const u16* A, const u16* Bt, float* Cf, u16* Cb,
                 const float* bias, int M, int N, int K, int lda, int ldb, int ldc,
                 long long sAb, long long sAh, long long sBb, long long sBh,
                 long long sCb, long long sCh, int nb, int nh, int mode,
                 int kclamp_off = 0, int flags = 0,
                 float* Pm = nullptr, float* Pl = nullptr)
{
  dim3 g((N + 127) / 128, (M + 127) / 128, nb * nh);
  if (Pm)
    k_gemm<1><<<g, 256, 0, st>>>(A, Bt, Cf, Cb, bias, M, N, K, lda, ldb, ldc,
                                 sAb, sAh, sBb, sBh, sCb, sCh, nh, mode,
                                 kclamp_off, flags, Pm, Pl);
  else
    k_gemm<0><<<g, 256, 0, st>>>(A, Bt, Cf, Cb, bias, M, N, K, lda, ldb, ldc,
                                 sAb, sAh, sBb, sBh, sCb, sCh, nh, mode,
                                 kclamp_off, flags, nullptr, nullptr);
}

extern "C" void kernel_launch(void* const* d_in, const int* in_sizes, int n_in,
                              void* d_out, int out_size, void* d_ws, size_t ws_size,
                              hipStream_t stream)
{
  const int*   tokens = (const int*)d_in[0];
  const float* memory = (const float*)d_in[1];
  const float* table  = (const float*)d_in[2];
  const float* Wq   = (const float*)d_in[3];
  const float* Wkv  = (const float*)d_in[4];
  const float* Wr   = (const float*)d_in[5];
  const float* Wo   = (const float*)d_in[6];
  const float* bq   = (const float*)d_in[7];
  const float* bkv  = (const float*)d_in[8];
  const float* br   = (const float*)d_in[9];
  const float* bo   = (const float*)d_in[10];
  const float* bctx = (const float*)d_in[11];
  const float* brel = (const float*)d_in[12];
  const float* ln1g = (const float*)d_in[13];
  const float* ln1b = (const float*)d_in[14];
  const float* W1   = (const float*)d_in[15];
  const float* b1   = (const float*)d_in[16];
  const float* W2   = (const float*)d_in[17];
  const float* b2   = (const float*)d_in[18];
  const float* ln2g = (const float*)d_in[19];
  const float* ln2b = (const float*)d_in[20];
  const float* Wout = (const float*)d_in[21];
  const float* bout = (const float*)d_in[22];
  float* out = (float*)d_out;

  char* w = (char*)d_ws;
  size_t off = 0;
  auto carve = [&](size_t bytes) -> char* {
    char* p = w + off;
    off = (off + bytes + 255) & ~(size_t)255;
    return p;
  };

  u16*  WqT    = (u16*)carve((size_t)U_ * U_ * 2);
  u16*  WkvT   = (u16*)carve((size_t)2 * U_ * U_ * 2);
  u16*  WrT    = (u16*)carve((size_t)U_ * U_ * 2);
  u16*  WoT    = (u16*)carve((size_t)U_ * U_ * 2);
  u16*  W1T    = (u16*)carve((size_t)FF_ * U_ * 2);
  u16*  W2T    = (u16*)carve((size_t)U_ * FF_ * 2);
  float* xf    = (float*)carve((size_t)BS_ * U_ * 4);
  u16*  xbf    = (u16*)carve((size_t)BS_ * U_ * 2);
  u16*  fullbf = (u16*)carve((size_t)BKL_ * U_ * 2);
  u16*  relbf  = (u16*)carve((size_t)KL_ * U_ * 2);
  float* qf    = (float*)carve((size_t)BS_ * U_ * 4);
  u16*  qcbf   = (u16*)carve((size_t)BS_ * U_ * 2);
  u16*  qrbf   = (u16*)carve((size_t)BS_ * U_ * 2);
  u16*  kvbf   = (u16*)carve((size_t)BKL_ * 2 * U_ * 2);
  u16*  vT     = (u16*)carve((size_t)B_ * H_ * D_ * KL_ * 2);
  u16*  rW     = (u16*)carve((size_t)KL_ * U_ * 2);
  u16*  attout = (u16*)carve((size_t)BS_ * U_ * 2);
  float* of    = (float*)carve((size_t)BS_ * U_ * 4);
  float* h1f   = (float*)carve((size_t)BS_ * U_ * 4);
  u16*  h1bf   = (u16*)carve((size_t)BS_ * U_ * 2);
  u16*  ff1bf  = (u16*)carve((size_t)BS_ * FF_ * 2);
  float* ff2f  = (float*)carve((size_t)BS_ * U_ * 4);
  u16*  h2bf   = (u16*)carve((size_t)BS_ * U_ * 2);

  // big region: C1 scores during attention; WoutT (64 MB) overlays it after
  size_t scoreBytes = (size_t)B_ * H_ * S_ * KL_ * 2;   // 104,857,600
  char* big = carve(scoreBytes);
  u16* C1    = (u16*)big;
  u16* WoutT = (u16*)big;

  // softmax partials (2048 x 250 fp32 each) overlay the dead q-bias buffers:
  // qcbf/qrbf (4 MB each) are last read by the score GEMMs, long before the
  // Wout GEMM that writes the partials.
  float* Pm = (float*)qcbf;
  float* Pl = (float*)qrbf;

  if (off > ws_size) return;  // workspace too small: fail cleanly, don't fault

  // ---- weight transposes (fp32 -> bf16, (R,C) -> (C,R)) ----
  k_transpose<<<dim3(U_ / 32, U_ / 32), 256, 0, stream>>>(Wq, WqT, U_, U_);
  k_transpose<<<dim3(2 * U_ / 32, U_ / 32), 256, 0, stream>>>(Wkv, WkvT, U_, 2 * U_);
  k_transpose<<<dim3(U_ / 32, U_ / 32), 256, 0, stream>>>(Wr, WrT, U_, U_);
  k_transpose<<<dim3(U_ / 32, U_ / 32), 256, 0, stream>>>(Wo, WoT, U_, U_);
  k_transpose<<<dim3(FF_ / 32, U_ / 32), 256, 0, stream>>>(W1, W1T, U_, FF_);
  k_transpose<<<dim3(U_ / 32, FF_ / 32), 256, 0, stream>>>(W2, W2T, FF_, U_);

  k_embed<<<dim3(BKL_), 256, 0, stream>>>(tokens, memory, table, fullbf, xbf, xf);
  k_relpos<<<dim3(KL_), 256, 0, stream>>>(relbf);

  // q = x@Wq + bq (fp32)
  gemm(stream, xbf, WqT, qf, nullptr, bq, BS_, U_, U_, U_, U_, U_,
       0, 0, 0, 0, 0, 0, 1, 1, 0);
  k_qbias<<<dim3(BS_), 256, 0, stream>>>(qf, bctx, brel, qcbf, qrbf);

  // kv = full@Wkv + bkv (bf16)
  gemm(stream, fullbf, WkvT, nullptr, kvbf, bkv, BKL_, 2 * U_, U_, U_, U_, 2 * U_,
       0, 0, 0, 0, 0, 0, 1, 1, 0);
  k_vt<<<dim3(KL_ / 32, 2, B_ * H_), 256, 0, stream>>>(kvbf, vT);

  // rW = rel@Wr + br (bf16)
  gemm(stream, relbf, WrT, nullptr, rW, br, KL_, U_, U_, U_, U_, U_,
       0, 0, 0, 0, 0, 0, 1, 1, 0);

  // C1 = q_c @ k^T  (batched over b,h; fully-masked tiles skipped)
  gemm(stream, qcbf, kvbf, nullptr, C1, nullptr,
       S_, KL_, D_, U_, 2 * U_, KL_,
       (long long)S_ * U_, 64, (long long)KL_ * 2 * U_, 64,
       (long long)H_ * S_ * KL_, (long long)S_ * KL_, B_, H_, 0, 0, 1);
  // C1 += rel-shift(q_r @ r^T)  (mode 2 epilogue; all-tc<0 tiles skipped)
  gemm(stream, qrbf, rW, nullptr, C1, nullptr,
       S_, KL_, D_, U_, U_, KL_,
       (long long)S_ * U_, 64, 0, 64,
       (long long)H_ * S_ * KL_, (long long)S_ * KL_, B_, H_, 2);

  k_attnsm<<<dim3(S_, B_ * H_), 256, 0, stream>>>(C1);

  // attout = att @ v (bf16, written as (B,S,H,D) == (B,S,U)); K clamped to
  // m0+MEM+128 (everything beyond is exactly zero after softmax)
  gemm(stream, C1, vT, nullptr, attout, nullptr,
       S_, D_, KL_, KL_, KL_, U_,
       (long long)H_ * S_ * KL_, (long long)S_ * KL_,
       (long long)H_ * D_ * KL_, (long long)D_ * KL_,
       (long long)S_ * U_, 64, B_, H_, 0, MEM_ + 128, 0);

  // of = attout@Wo + bo (fp32)
  gemm(stream, attout, WoT, of, nullptr, bo, BS_, U_, U_, U_, U_, U_,
       0, 0, 0, 0, 0, 0, 1, 1, 0);
  k_ln<<<dim3(BS_), 256, 0, stream>>>(xf, of, ln1g, ln1b, h1f, h1bf);

  // ff1 = relu(h1@W1 + b1) (bf16)
  gemm(stream, h1bf, W1T, nullptr, ff1bf, b1, BS_, FF_, U_, U_, U_, FF_,
       0, 0, 0, 0, 0, 0, 1, 1, 1);
  // ff2 = ff1@W2 + b2 (fp32)
  gemm(stream, ff1bf, W2T, ff2f, nullptr, b2, BS_, U_, FF_, FF_, FF_, U_,
       0, 0, 0, 0, 0, 0, 1, 1, 0);
  k_ln<<<dim3(BS_), 256, 0, stream>>>(h1f, ff2f, ln2g, ln2b, nullptr, h2bf);

  // scores region free now (att consumed) -> WoutT overlays it
  k_transpose<<<dim3(NT_ / 32, U_ / 32), 256, 0, stream>>>(Wout, WoutT, U_, NT_);

  // logits = h2@Wout + bout, fp32 straight into d_out, with fused softmax
  // pass-1 (per-tile row max / sum-of-exp partials); then one-pass softmax
  gemm(stream, h2bf, WoutT, out, nullptr, bout, BS_, NT_, U_, U_, U_, NT_,
       0, 0, 0, 0, 0, 0, 1, 1, 0, 0, 0, Pm, Pl);
  k_outsm2<<<dim3(BS_), 256, 0, stream>>>(out, Pm, Pl, NT_ / 128);
}